// Round 1
// baseline (1363.482 us; speedup 1.0000x reference)
//
#include <hip/hip_runtime.h>
#include <math.h>

namespace {
constexpr int kT = 8, kL = 8, kN = 500, kD = 64, kK = 12, kS = 2;
constexpr int kLN  = kL * kN;        // 4000
constexpr int kTLN = kT * kL * kN;   // 32000
constexpr int kBUF = kTLN * kD;      // 2,048,000 floats = 8.19 MB
}

__device__ __forceinline__ float sigf(float v) { return 1.f / (1.f + expf(-v)); }

// One wave (64 lanes) per (l,n) row. new = sigmoid(cat(now,st)@w1 * th + now*(1-th))
__global__ void evo_kernel(const float* __restrict__ st, const float* __restrict__ th,
                           const float* __restrict__ prev, float* __restrict__ cur,
                           float* __restrict__ diff, const float* __restrict__ w1) {
    int row = blockIdx.x;          // l*N + n
    int d   = threadIdx.x;         // 0..63
    float xn = prev[(size_t)row * kD + d];
    float xs = st[(size_t)row * kD + d];
    float t  = th[row];
    float y = 0.f;
#pragma unroll 16
    for (int j = 0; j < kD; ++j) {
        float a = __shfl(xn, j);
        y = fmaf(a, w1[j * kD + d], y);
    }
#pragma unroll 16
    for (int j = 0; j < kD; ++j) {
        float a = __shfl(xs, j);
        y = fmaf(a, w1[(kD + j) * kD + d], y);
    }
    float nv = sigf(y * t + xn * (1.f - t));
    cur[(size_t)row * kD + d]  = nv;
    diff[(size_t)row * kD + d] = nv - xn;
}

// Y = X @ W   (W is 64x64 row-major). One wave per row; 4 waves per block.
__global__ void xw_kernel(const float* __restrict__ X, const float* __restrict__ W,
                          float* __restrict__ Y) {
    int wave = threadIdx.x >> 6;
    int lane = threadIdx.x & 63;
    int row  = blockIdx.x * 4 + wave;
    float x = X[(size_t)row * kD + lane];
    float y = 0.f;
#pragma unroll 16
    for (int j = 0; j < kD; ++j) {
        float a = __shfl(x, j);
        y = fmaf(a, W[j * kD + lane], y);
    }
    Y[(size_t)row * kD + lane] = y;
}

// Fused attention: q = x@wq; gather XK rows of the 12 neighbors (same (t,l) slab);
// scores -> softmax -> out = q + sum a_j k_j; Y = sigmoid(out @ wd).
__global__ void attn_kernel(const float* __restrict__ X, const float* __restrict__ XK,
                            const int* __restrict__ neigh,
                            const float* __restrict__ wq, const float* __restrict__ wd,
                            float* __restrict__ Y) {
    int wave = threadIdx.x >> 6;
    int lane = threadIdx.x & 63;
    int row  = blockIdx.x * 4 + wave;   // (t*L + l)*N + n
    int n    = row % kN;
    int slab = row - n;                 // (t*L + l)*N
    float x = X[(size_t)row * kD + lane];
    // q = x @ wq
    float q = 0.f;
#pragma unroll 16
    for (int j = 0; j < kD; ++j) {
        float a = __shfl(x, j);
        q = fmaf(a, wq[j * kD + lane], q);
    }
    // gather neighbor keys, raw scores
    float kv[kK], sc[kK];
#pragma unroll
    for (int j = 0; j < kK; ++j) {
        int nb = neigh[n * kK + j];
        kv[j] = XK[(size_t)(slab + nb) * kD + lane];
        sc[j] = q * kv[j];
    }
    // wave-wide reduce of each score (butterfly -> all lanes hold full sum)
#pragma unroll
    for (int off = 32; off > 0; off >>= 1) {
#pragma unroll
        for (int j = 0; j < kK; ++j) sc[j] += __shfl_xor(sc[j], off);
    }
    // softmax over K
    float m = sc[0];
#pragma unroll
    for (int j = 1; j < kK; ++j) m = fmaxf(m, sc[j]);
    float ssum = 0.f;
#pragma unroll
    for (int j = 0; j < kK; ++j) { sc[j] = expf(sc[j] - m); ssum += sc[j]; }
    float inv = 1.f / ssum;
    float o = q;
#pragma unroll
    for (int j = 0; j < kK; ++j) o = fmaf(sc[j] * inv, kv[j], o);
    // y = sigmoid(out @ wd)
    float y = 0.f;
#pragma unroll 16
    for (int j = 0; j < kD; ++j) {
        float a = __shfl(o, j);
        y = fmaf(a, wd[j * kD + lane], y);
    }
    Y[(size_t)row * kD + lane] = sigf(y);
}

// acc = (init ? 0 : acc) + xg * wmix[d];  if fin: acc = sigmoid(acc)
__global__ void mix_kernel(const float* __restrict__ xg, const float* __restrict__ wmix,
                           float* __restrict__ acc, int init, int fin) {
    int i = blockIdx.x * blockDim.x + threadIdx.x;
    float w = wmix[i & (kD - 1)];
    float v = xg[i] * w + (init ? 0.f : acc[i]);
    if (fin) v = sigf(v);
    acc[i] = v;
}

// One thread per (t,n) cell; sequential over l. x = concat(mixd, mixs) along feature.
__global__ void lstm_kernel(const float* __restrict__ md, const float* __restrict__ ms,
                            const float* __restrict__ cw, const float* __restrict__ cb,
                            float* __restrict__ hlast) {
    int idx = blockIdx.x * blockDim.x + threadIdx.x;
    if (idx >= kT * kN) return;
    int t = idx / kN, n = idx % kN;
    float h = 0.f, c = 0.f;
    float b0 = cb[0], b1 = cb[1], b2 = cb[2], b3 = cb[3];
    for (int l = 0; l < kL; ++l) {
        size_t ofs = ((size_t)(t * kL + l) * kN + n) * kD;
        const float* xd = md + ofs;
        const float* xs = ms + ofs;
        float g0 = b0 + h * cw[0 * 129 + 128];
        float g1 = b1 + h * cw[1 * 129 + 128];
        float g2 = b2 + h * cw[2 * 129 + 128];
        float g3 = b3 + h * cw[3 * 129 + 128];
#pragma unroll 8
        for (int dd = 0; dd < kD; ++dd) {
            float v = xd[dd];
            g0 = fmaf(v, cw[0 * 129 + dd], g0);
            g1 = fmaf(v, cw[1 * 129 + dd], g1);
            g2 = fmaf(v, cw[2 * 129 + dd], g2);
            g3 = fmaf(v, cw[3 * 129 + dd], g3);
        }
#pragma unroll 8
        for (int dd = 0; dd < kD; ++dd) {
            float v = xs[dd];
            g0 = fmaf(v, cw[0 * 129 + 64 + dd], g0);
            g1 = fmaf(v, cw[1 * 129 + 64 + dd], g1);
            g2 = fmaf(v, cw[2 * 129 + 64 + dd], g2);
            g3 = fmaf(v, cw[3 * 129 + 64 + dd], g3);
        }
        float ii = sigf(g0);
        float ff = sigf(g1);
        float oo = sigf(g2);
        float gt = tanhf(g3);
        c = ff * c + ii * gt;
        h = oo * tanhf(c);
    }
    hlast[idx] = h;
}

// out[t,m] = sigmoid(sum_n h[t,n]*fw[m,n] + fb[m]); one wave per output.
__global__ void final_kernel(const float* __restrict__ h, const float* __restrict__ fw,
                             const float* __restrict__ fb, float* __restrict__ out) {
    int wave = threadIdx.x >> 6, lane = threadIdx.x & 63;
    int o = blockIdx.x * 4 + wave;   // t*N + m
    int t = o / kN, m = o % kN;
    float acc = 0.f;
    for (int n = lane; n < kN; n += 64)
        acc = fmaf(h[t * kN + n], fw[(size_t)m * kN + n], acc);
#pragma unroll
    for (int off = 32; off > 0; off >>= 1) acc += __shfl_xor(acc, off);
    if (lane == 0) out[o] = sigf(acc + fb[m]);
}

extern "C" void kernel_launch(void* const* d_in, const int* in_sizes, int n_in,
                              void* d_out, int out_size, void* d_ws, size_t ws_size,
                              hipStream_t stream) {
    const float* stat   = (const float*)d_in[0];   // (T,L,N,D)
    const float* thre   = (const float*)d_in[1];   // (T,L,N,1)
    const float* dyn0   = (const float*)d_in[2];   // (L,N,D)
    const int*   npoi   = (const int*)d_in[3];
    const int*   nroad  = (const int*)d_in[4];
    const int*   nrec   = (const int*)d_in[5];
    const float* w1     = (const float*)d_in[6];   // (2D, D)
    const float* wq_all = (const float*)d_in[7];   // (2,3,S,D,D)
    const float* wk_all = (const float*)d_in[8];
    const float* wd_all = (const float*)d_in[9];
    const float* wmix   = (const float*)d_in[10];  // (2,3,D)
    const float* conv_w = (const float*)d_in[11];  // (4,129)
    const float* conv_b = (const float*)d_in[12];  // (4,)
    const float* fin_w  = (const float*)d_in[13];  // (N,N)
    const float* fin_b  = (const float*)d_in[14];  // (N,)

    float* out       = (float*)d_out;              // (T,N) = 4000
    float* now_final = out + kT * kN;              // (L,N,D) = 256000
    float* diffs     = now_final + (size_t)kLN * kD; // (T-1,L,N,D)

    float* ws      = (float*)d_ws;
    float* all_dyn = ws;                           // (T,L,N,D)
    float* xk      = ws + (size_t)kBUF;
    float* xa      = ws + 2 * (size_t)kBUF;
    float* xb      = ws + 3 * (size_t)kBUF;
    float* mixd    = ws + 4 * (size_t)kBUF;
    float* mixs    = ws + 5 * (size_t)kBUF;
    float* hlast   = ws + 6 * (size_t)kBUF;        // (T,N)

    // ---- evolution scan (sequential over t) ----
    hipMemcpyAsync(all_dyn, dyn0, sizeof(float) * kLN * kD,
                   hipMemcpyDeviceToDevice, stream);
    for (int t = 1; t < kT; ++t) {
        evo_kernel<<<kLN, 64, 0, stream>>>(
            stat + (size_t)t * kLN * kD, thre + (size_t)t * kLN,
            all_dyn + (size_t)(t - 1) * kLN * kD,
            all_dyn + (size_t)t * kLN * kD,
            diffs + (size_t)(t - 1) * kLN * kD, w1);
    }
    hipMemcpyAsync(now_final, all_dyn + (size_t)(kT - 1) * kLN * kD,
                   sizeof(float) * kLN * kD, hipMemcpyDeviceToDevice, stream);

    // ---- two multiattention paths ----
    const int* neighs[3] = {npoi, nroad, nrec};
    for (int m = 0; m < 2; ++m) {
        const float* input = (m == 0) ? all_dyn : stat;
        float* mix = (m == 0) ? mixd : mixs;
        for (int g = 0; g < 3; ++g) {
            size_t o0 = (size_t)((m * 3 + g) * kS + 0) * kD * kD;
            size_t o1 = (size_t)((m * 3 + g) * kS + 1) * kD * kD;
            // step s=0: input -> xa
            xw_kernel<<<kTLN / 4, 256, 0, stream>>>(input, wk_all + o0, xk);
            attn_kernel<<<kTLN / 4, 256, 0, stream>>>(input, xk, neighs[g],
                                                      wq_all + o0, wd_all + o0, xa);
            // step s=1: xa -> xb
            xw_kernel<<<kTLN / 4, 256, 0, stream>>>(xa, wk_all + o1, xk);
            attn_kernel<<<kTLN / 4, 256, 0, stream>>>(xa, xk, neighs[g],
                                                      wq_all + o1, wd_all + o1, xb);
            // accumulate group into mix; sigmoid on last group
            mix_kernel<<<kBUF / 256, 256, 0, stream>>>(
                xb, wmix + (size_t)(m * 3 + g) * kD, mix,
                (g == 0) ? 1 : 0, (g == 2) ? 1 : 0);
        }
    }

    // ---- LSTM over l, then final projection ----
    lstm_kernel<<<(kT * kN + 255) / 256, 256, 0, stream>>>(mixd, mixs, conv_w, conv_b, hlast);
    final_kernel<<<kT * kN / 4, 256, 0, stream>>>(hlast, fin_w, fin_b, out);
}